// Round 3
// baseline (273.633 us; speedup 1.0000x reference)
//
#include <hip/hip_runtime.h>

#define NCLS 19
#define HW (512 * 512)
#define NPIX (8 * HW)
#define NGRP4 (NPIX / 4)         // 524288 groups of 4 pixels
#define BLOCKS 2048
#define THREADS 256
// TOT = 524288 threads -> exactly 1 group of 4 pixels per thread

// ws layout: per-block partial rows of 64 floats.
// row[0..18]=intersection  row[19..37]=prob_sums  row[38..56]=counts
// row[57]=sum_wnll  row[58]=focal_sum
#define ROW 64

__global__ __launch_bounds__(THREADS, 4)
void focal_dice_main(const float* __restrict__ logits,
                     const int*   __restrict__ target,
                     const float* __restrict__ cw,
                     const float* __restrict__ fa,
                     float*       __restrict__ ws)
{
    __shared__ float sh_cw[NCLS], sh_fa[NCLS];
    __shared__ float sh_inter[NCLS], sh_cnt[NCLS], sh_psum[NCLS];
    __shared__ float sh_scal[2];

    const int tid = threadIdx.x;
    if (tid < NCLS) {
        sh_cw[tid] = cw[tid];
        sh_fa[tid] = fa[tid];
        sh_inter[tid] = 0.f; sh_cnt[tid] = 0.f; sh_psum[tid] = 0.f;
    }
    if (tid < 2) sh_scal[tid] = 0.f;
    __syncthreads();

    const unsigned g   = blockIdx.x * (unsigned)THREADS + (unsigned)tid;
    const unsigned b   = g >> 16;                    // 65536 groups per image
    const unsigned hw4 = g & 65535u;

    const float4* lp = reinterpret_cast<const float4*>(logits)
                     + (size_t)b * (size_t)(NCLS * (HW / 4)) + hw4;
    const int4 t4 = reinterpret_cast<const int4*>(target)[g];

    // ---- load 19 classes x 4 pixels (one batch, max MLP) ----
    float4 x[NCLS];
#pragma unroll
    for (int c = 0; c < NCLS; ++c)
        x[c] = lp[(size_t)c * (HW / 4)];

    // ---- max over classes (per pixel) ----
    float4 mx = x[0];
#pragma unroll
    for (int c = 1; c < NCLS; ++c) {
        mx.x = fmaxf(mx.x, x[c].x);
        mx.y = fmaxf(mx.y, x[c].y);
        mx.z = fmaxf(mx.z, x[c].z);
        mx.w = fmaxf(mx.w, x[c].w);
    }

    // ---- exp / sum; grab e_t on the fly ----
    float4 s  = make_float4(0.f, 0.f, 0.f, 0.f);
    float4 et = make_float4(0.f, 0.f, 0.f, 0.f);
#pragma unroll
    for (int c = 0; c < NCLS; ++c) {
        float4 e;
        e.x = __expf(x[c].x - mx.x);
        e.y = __expf(x[c].y - mx.y);
        e.z = __expf(x[c].z - mx.z);
        e.w = __expf(x[c].w - mx.w);
        s.x += e.x; s.y += e.y; s.z += e.z; s.w += e.w;
        if (t4.x == c) et.x = e.x;
        if (t4.y == c) et.y = e.y;
        if (t4.z == c) et.z = e.z;
        if (t4.w == c) et.w = e.w;
        x[c] = e;   // keep e_c for prob_sums accumulation
    }

    float4 rs;
    rs.x = __builtin_amdgcn_rcpf(s.x);
    rs.y = __builtin_amdgcn_rcpf(s.y);
    rs.z = __builtin_amdgcn_rcpf(s.z);
    rs.w = __builtin_amdgcn_rcpf(s.w);

    // ---- per-pixel pt / log_pt ----
    float4 pt, lpt;
    pt.x = et.x * rs.x;  pt.y = et.y * rs.y;
    pt.z = et.z * rs.z;  pt.w = et.w * rs.w;
    lpt.x = __logf(pt.x); lpt.y = __logf(pt.y);
    lpt.z = __logf(pt.z); lpt.w = __logf(pt.w);

    float4 ptc;  // clamped pt for focal factor
    ptc.x = fmaxf(pt.x, 1e-8f); ptc.y = fmaxf(pt.y, 1e-8f);
    ptc.z = fmaxf(pt.z, 1e-8f); ptc.w = fmaxf(pt.w, 1e-8f);

    const float w0 = sh_cw[t4.x], w1 = sh_cw[t4.y], w2 = sh_cw[t4.z], w3 = sh_cw[t4.w];
    const float a0 = sh_fa[t4.x], a1 = sh_fa[t4.y], a2 = sh_fa[t4.z], a3 = sh_fa[t4.w];

    float v_wnll = -(w0 * lpt.x + w1 * lpt.y + w2 * lpt.z + w3 * lpt.w);
    const float o0 = 1.f - ptc.x, o1 = 1.f - ptc.y, o2 = 1.f - ptc.z, o3 = 1.f - ptc.w;
    float v_foc = -(a0 * o0 * o0 * lpt.x + a1 * o1 * o1 * lpt.y +
                    a2 * o2 * o2 * lpt.z + a3 * o3 * o3 * lpt.w);

    // ---- intersection & counts: LDS atomics (scattered by target) ----
    atomicAdd(&sh_inter[t4.x], pt.x);
    atomicAdd(&sh_inter[t4.y], pt.y);
    atomicAdd(&sh_inter[t4.z], pt.z);
    atomicAdd(&sh_inter[t4.w], pt.w);
    atomicAdd(&sh_cnt[t4.x], 1.f);
    atomicAdd(&sh_cnt[t4.y], 1.f);
    atomicAdd(&sh_cnt[t4.z], 1.f);
    atomicAdd(&sh_cnt[t4.w], 1.f);

    // ---- wave reductions ----
    auto wsum = [](float v) {
        v += __shfl_xor(v, 1);
        v += __shfl_xor(v, 2);
        v += __shfl_xor(v, 4);
        v += __shfl_xor(v, 8);
        v += __shfl_xor(v, 16);
        v += __shfl_xor(v, 32);
        return v;
    };

    const int lane = tid & 63;
    v_wnll = wsum(v_wnll);
    v_foc  = wsum(v_foc);
    if (lane == 0) {
        atomicAdd(&sh_scal[0], v_wnll);
        atomicAdd(&sh_scal[1], v_foc);
    }
#pragma unroll
    for (int c = 0; c < NCLS; ++c) {
        float pc = x[c].x * rs.x + x[c].y * rs.y + x[c].z * rs.z + x[c].w * rs.w;
        float v = wsum(pc);
        if (lane == c) atomicAdd(&sh_psum[c], v);
    }

    __syncthreads();

    // ---- contention-free per-block partial row (plain coalesced stores) ----
    float* prow = ws + (size_t)blockIdx.x * ROW;
    if (tid < NCLS) {
        prow[tid]            = sh_inter[tid];
        prow[NCLS + tid]     = sh_psum[tid];
        prow[2 * NCLS + tid] = sh_cnt[tid];
    } else if (tid == 64) {
        prow[57] = sh_scal[0];
    } else if (tid == 65) {
        prow[58] = sh_scal[1];
    }
}

__global__ __launch_bounds__(1024)
void focal_dice_final(const float* __restrict__ ws,
                      const float* __restrict__ cw,
                      float*       __restrict__ out)
{
    __shared__ float sh[16][ROW];
    const int v  = threadIdx.x & 63;   // which value in the row
    const int ch = threadIdx.x >> 6;   // chunk 0..15

    float acc = 0.f;
    for (int b = ch; b < BLOCKS; b += 16)
        acc += ws[(size_t)b * ROW + v];
    sh[ch][v] = acc;
    __syncthreads();

    if (threadIdx.x < ROW) {
        float t = 0.f;
#pragma unroll
        for (int i = 0; i < 16; ++i) t += sh[i][v];
        sh[0][v] = t;          // each thread touches only its own column
    }
    __syncthreads();

    if (threadIdx.x == 0) {
        const float* r = &sh[0][0];
        float sum_w = 0.f;
        for (int c = 0; c < NCLS; ++c) sum_w += cw[c] * r[2 * NCLS + c];
        const float ce    = r[57] / sum_w;
        const float focal = r[58] * (1.f / (float)NPIX);
        float cwsum = 0.f;
        for (int c = 0; c < NCLS; ++c) cwsum += cw[c];
        const float inv = 1.f / fmaxf(cwsum, 1e-8f);
        float dsum = 0.f;
        for (int c = 0; c < NCLS; ++c) {
            const float I   = r[c];
            const float S   = r[NCLS + c];
            const float cnt = r[2 * NCLS + c];
            const float dice = (2.f * I + 1.f) / (S + cnt + 1.f);
            dsum += dice * cw[c] * inv;
        }
        out[0] = 0.4f * ce + 0.3f * focal + 0.3f * (1.f - dsum);
    }
}

extern "C" void kernel_launch(void* const* d_in, const int* in_sizes, int n_in,
                              void* d_out, int out_size, void* d_ws, size_t ws_size,
                              hipStream_t stream)
{
    const float* logits = (const float*)d_in[0];
    const int*   target = (const int*)d_in[1];
    const float* cw     = (const float*)d_in[2];
    const float* fa     = (const float*)d_in[3];
    float* ws  = (float*)d_ws;
    float* out = (float*)d_out;

    // no memset needed: every partial row is fully overwritten each launch
    focal_dice_main<<<BLOCKS, THREADS, 0, stream>>>(logits, target, cw, fa, ws);
    focal_dice_final<<<1, 1024, 0, stream>>>(ws, cw, out);
}